// Round 2
// baseline (206.898 us; speedup 1.0000x reference)
//
#include <hip/hip_runtime.h>

#define LSEQ 512
#define BATCH 1024
#define T 48

// ---------------------------------------------------------------------------
// Kernel 1: forward algorithm (denominator). One wave (64 lanes) per batch
// element; lane j owns state j (j>=48 are dummy lanes pinned to -1e30).
// E[:,j] = exp(trans[:,j]) held in 48 VGPRs per lane. Cross-lane broadcast of
// p[i] = exp(alpha[i]-ref) via v_readlane (compile-time lane index), so the
// 511-step main loop has no LDS traffic and no barriers.
// grid: 256 blocks x 256 threads (4 waves/block -> 1024 waves = 1024 batches)
// ---------------------------------------------------------------------------
__global__ __launch_bounds__(256) void crf_forward(
    const float* __restrict__ emissions,      // (L,B,T)
    const int* __restrict__ mask,             // (L,B) bool -> int32
    const float* __restrict__ start_tr,       // (T)
    const float* __restrict__ end_tr,         // (T)
    const float* __restrict__ trans,          // (T,T)
    float* __restrict__ denom_out)            // (B)
{
    const int wave = threadIdx.x >> 6;
    const int lane = threadIdx.x & 63;
    const int b    = blockIdx.x * 4 + wave;
    const int j    = lane;
    const bool valid = (j < T);
    const int jc   = valid ? j : (T - 1);   // clamped for safe addressing

    // E column in registers: E_col[i] = exp(trans[i][j])
    float E_col[T];
    #pragma unroll
    for (int i = 0; i < T; ++i) {
        E_col[i] = __expf(trans[i * T + jc]);
    }

    // alpha init: start + emissions[0]
    float alpha = valid ? (start_tr[jc] + emissions[((size_t)0 * BATCH + b) * T + jc])
                        : -1e30f;

    // 2-deep prefetch of emissions[t][b][j] and mask[t][b]
    float em_a = emissions[((size_t)1 * BATCH + b) * T + jc];
    float em_b = emissions[((size_t)2 * BATCH + b) * T + jc];
    int mk_a = mask[1 * BATCH + b];
    int mk_b = mask[2 * BATCH + b];

    for (int t = 1; t < LSEQ; ++t) {
        const float em_t = em_a;  em_a = em_b;
        const int mt = mk_a;  mk_a = mk_b;
        int tn = t + 2; if (tn > LSEQ - 1) tn = LSEQ - 1;
        em_b = emissions[((size_t)tn * BATCH + b) * T + jc];
        mk_b = mask[tn * BATCH + b];

        // reference value = lane 0's alpha (bounded spread, no exact max needed)
        const float ref = __int_as_float(
            __builtin_amdgcn_readlane(__float_as_int(alpha), 0));
        const float p = __expf(alpha - ref);    // dummy lanes: exp(-1e30)=0
        const int pbits = __float_as_int(p);

        float s0 = 0.f, s1 = 0.f, s2 = 0.f, s3 = 0.f;
        #pragma unroll
        for (int i = 0; i < T; i += 4) {
            s0 = __builtin_fmaf(__int_as_float(__builtin_amdgcn_readlane(pbits, i    )), E_col[i    ], s0);
            s1 = __builtin_fmaf(__int_as_float(__builtin_amdgcn_readlane(pbits, i + 1)), E_col[i + 1], s1);
            s2 = __builtin_fmaf(__int_as_float(__builtin_amdgcn_readlane(pbits, i + 2)), E_col[i + 2], s2);
            s3 = __builtin_fmaf(__int_as_float(__builtin_amdgcn_readlane(pbits, i + 3)), E_col[i + 3], s3);
        }
        const float s = (s0 + s1) + (s2 + s3);
        const float anew = em_t + ref + __logf(s);
        if (mt && valid) alpha = anew;          // masked update; dummies stay -1e30
    }

    // denominator = LSE_j(alpha + end_tr[j]) across the wave
    float v = valid ? (alpha + end_tr[jc]) : -1e30f;
    float m = v;
    #pragma unroll
    for (int off = 32; off > 0; off >>= 1) m = fmaxf(m, __shfl_xor(m, off));
    float e = __expf(v - m);
    #pragma unroll
    for (int off = 32; off > 0; off >>= 1) e += __shfl_xor(e, off);
    if (lane == 0) denom_out[b] = m + __logf(e);
}

// ---------------------------------------------------------------------------
// Kernel 2: numerator partial sums over t-chunks of 64 steps.
// gid = c*1024 + b; chunk c covers t in [c*64, c*64+64) (chunk 0 skips t=0 for
// the transition/emission terms but counts mask[0]).
// grid: 32 blocks x 256 threads
// ---------------------------------------------------------------------------
__global__ __launch_bounds__(256) void crf_score_partial(
    const float* __restrict__ emissions,
    const int* __restrict__ tags,             // (L,B)
    const int* __restrict__ mask,             // (L,B) bool -> int32
    const float* __restrict__ trans,          // (T,T)
    float* __restrict__ part,                 // (8, B)
    int* __restrict__ cnt)                    // (8, B)
{
    const int gid = blockIdx.x * blockDim.x + threadIdx.x;
    const int b = gid & (BATCH - 1);
    const int c = gid >> 10;
    const int t0 = c * 64;
    const int t1 = t0 + 64;

    float sc = 0.f;
    int ct = 0;
    const int tstart = (t0 == 0) ? 1 : t0;
    if (t0 == 0) ct += mask[b] ? 1 : 0;       // t = 0 contributes to count only

    int tag_prev = tags[(tstart - 1) * BATCH + b];
    for (int t = tstart; t < t1; ++t) {
        const int tag = tags[t * BATCH + b];
        const int mt = mask[t * BATCH + b];
        if (mt) {
            sc += trans[tag_prev * T + tag]
                + emissions[((size_t)t * BATCH + b) * T + tag];
            ct += 1;
        }
        tag_prev = tag;                       // raw previous tag, per reference
    }
    part[gid] = sc;
    cnt[gid] = ct;
}

// ---------------------------------------------------------------------------
// Kernel 3: combine partials + start/end terms, subtract denominator,
// mean-reduce over batch. 1 block x 1024 threads.
// ---------------------------------------------------------------------------
__global__ __launch_bounds__(1024) void crf_combine(
    const float* __restrict__ emissions,
    const int* __restrict__ tags,
    const float* __restrict__ start_tr,
    const float* __restrict__ end_tr,
    const float* __restrict__ part,
    const int* __restrict__ cnt,
    const float* __restrict__ denom,
    float* __restrict__ out)
{
    const int b = threadIdx.x;

    const int tag0 = tags[b];
    float sc = start_tr[tag0] + emissions[(size_t)b * T + tag0];
    int ct = 0;
    #pragma unroll
    for (int c = 0; c < 8; ++c) {
        sc += part[c * BATCH + b];
        ct += cnt[c * BATCH + b];
    }
    if (ct < 1) ct = 1;                        // guard (mask all-zero)
    const int last_tag = tags[(ct - 1) * BATCH + b];
    sc += end_tr[last_tag];

    const float llh = sc - denom[b];

    __shared__ float red[1024];
    red[b] = llh;
    __syncthreads();
    #pragma unroll
    for (int s = 512; s > 0; s >>= 1) {
        if (b < s) red[b] += red[b + s];
        __syncthreads();
    }
    if (b == 0) out[0] = red[0] / (float)BATCH;
}

extern "C" void kernel_launch(void* const* d_in, const int* in_sizes, int n_in,
                              void* d_out, int out_size, void* d_ws, size_t ws_size,
                              hipStream_t stream) {
    const float* emissions        = (const float*)d_in[0];
    const int* tags               = (const int*)d_in[1];
    const int* mask               = (const int*)d_in[2];
    const float* start_tr         = (const float*)d_in[3];
    const float* end_tr           = (const float*)d_in[4];
    const float* trans            = (const float*)d_in[5];
    float* out                    = (float*)d_out;

    float* denom = (float*)d_ws;          // 1024 floats
    float* part  = denom + BATCH;         // 8*1024 floats
    int*   cnt   = (int*)(part + 8 * BATCH); // 8*1024 ints

    crf_forward<<<256, 256, 0, stream>>>(emissions, mask, start_tr, end_tr, trans, denom);
    crf_score_partial<<<32, 256, 0, stream>>>(emissions, tags, mask, trans, part, cnt);
    crf_combine<<<1, 1024, 0, stream>>>(emissions, tags, start_tr, end_tr,
                                        part, cnt, denom, out);
}

// Round 4
// 198.036 us; speedup vs baseline: 1.0448x; 1.0448x over previous
//
#include <hip/hip_runtime.h>

#define LSEQ 512
#define BATCH 1024
#define T 48

// NOTE: __builtin_amdgcn_cvt_pkrtz returns __fp16 ext_vector(2), not _Float16
typedef __fp16 h2_t __attribute__((ext_vector_type(2)));

static __device__ __forceinline__ float bcast_lane0(float x) {
    return __int_as_float(__builtin_amdgcn_readfirstlane(__float_as_int(x)));
}

static __device__ __forceinline__ float dot2acc(int pk_bits, h2_t e, float acc) {
#if __has_builtin(__builtin_amdgcn_fdot2)
    return __builtin_amdgcn_fdot2(__builtin_bit_cast(h2_t, pk_bits), e, acc, false);
#else
    h2_t a = __builtin_bit_cast(h2_t, pk_bits);
    return __builtin_fmaf((float)a.x, (float)e.x,
           __builtin_fmaf((float)a.y, (float)e.y, acc));
#endif
}

static __device__ __forceinline__ float fast_rcp(float x) {
#if __has_builtin(__builtin_amdgcn_rcpf)
    return __builtin_amdgcn_rcpf(x);
#else
    return 1.0f / x;
#endif
}

// pack (w_j, w_{j+1}) into one 32-bit f16 pair at every lane.
// row_shr:1 (DppCtrl 0x111): lane j reads lane j+1. Even lanes 0..46 read odd
// lanes 1..47 -> never crosses a 16-lane DPP row. (row_shl:1 would be w_{j-1}!)
static __device__ __forceinline__ int pack_pairs(float w) {
    int wsh = __builtin_amdgcn_update_dpp(0, __float_as_int(w), 0x111, 0xF, 0xF, true);
    return __builtin_bit_cast(int, __builtin_amdgcn_cvt_pkrtz(w, __int_as_float(wsh)));
}

// ---------------------------------------------------------------------------
// Kernel 1: forward algorithm (denominator), linear-space recurrence.
// One wave per batch b; lane j owns state j (j>=48: w pinned to 0).
// Invariant: alpha_t[j] = C + log w[j], with w[0] == 1.
// Step:  S[j] = sum_i w[i]*E[i][j]   (24 x v_dot2_f32_f16; broadcast via
//        readlane of packed f16 pairs at even lanes)
//        w'[j] = exp(em[j]-em[0]) * S[j] / S[0];  C += em[0] + log(S[0])
// No LDS, no barriers; exp/log/rcp are wave-uniform or off the w->S->w path.
// ---------------------------------------------------------------------------
__global__ __launch_bounds__(256, 1) void crf_forward(
    const float* __restrict__ emissions,      // (L,B,T)
    const int* __restrict__ mask,             // (L,B) bool->int32
    const float* __restrict__ start_tr,       // (T)
    const float* __restrict__ end_tr,         // (T)
    const float* __restrict__ trans,          // (T,T)
    float* __restrict__ denom_out)            // (B)
{
    const int wave = threadIdx.x >> 6;
    const int lane = threadIdx.x & 63;
    const int b    = blockIdx.x * 4 + wave;
    const bool valid = (lane < T);
    const int jc   = valid ? lane : (T - 1);

    // E column pairs in f16: Ep[k] = (exp(trans[2k][j]), exp(trans[2k+1][j]))
    h2_t Ep[T / 2];
    #pragma unroll
    for (int k = 0; k < T / 2; ++k) {
        float e0 = __expf(trans[(2 * k) * T + jc]);
        float e1 = __expf(trans[(2 * k + 1) * T + jc]);
        Ep[k] = __builtin_amdgcn_cvt_pkrtz(e0, e1);
    }

    // init: alpha0 = start + em[0];  w = exp(alpha0 - alpha0[0]); C = alpha0[0]
    const float a0 = start_tr[jc] + emissions[(size_t)b * T + jc];
    const float A0 = bcast_lane0(a0);
    float w = valid ? __expf(a0 - A0) : 0.f;
    float C = A0;
    int pk = pack_pairs(w);

    // 4-deep prefetch (named registers, SSA-rotated)
    float em0_ = emissions[((size_t)1 * BATCH + b) * T + jc];
    float em1_ = emissions[((size_t)2 * BATCH + b) * T + jc];
    float em2_ = emissions[((size_t)3 * BATCH + b) * T + jc];
    float em3_ = emissions[((size_t)4 * BATCH + b) * T + jc];
    int   mk0_ = mask[1 * BATCH + b];
    int   mk1_ = mask[2 * BATCH + b];
    int   mk2_ = mask[3 * BATCH + b];
    int   mk3_ = mask[4 * BATCH + b];

    for (int t = 1; t <= LSEQ - 1; ++t) {
        const float em = em0_;  em0_ = em1_; em1_ = em2_; em2_ = em3_;
        const int   mk = mk0_;  mk0_ = mk1_; mk1_ = mk2_; mk2_ = mk3_;
        int tn = t + 4; if (tn > LSEQ - 1) tn = LSEQ - 1;
        em3_ = emissions[((size_t)tn * BATCH + b) * T + jc];
        mk3_ = mask[tn * BATCH + b];

        const float em0 = bcast_lane0(em);
        const float e   = __expf(em - em0);       // off critical path (prefetched em)

        float acc0 = 0.f, acc1 = 0.f, acc2 = 0.f, acc3 = 0.f;
        #pragma unroll
        for (int k = 0; k < T / 2; k += 4) {
            acc0 = dot2acc(__builtin_amdgcn_readlane(pk, 2 * k + 0), Ep[k + 0], acc0);
            acc1 = dot2acc(__builtin_amdgcn_readlane(pk, 2 * k + 2), Ep[k + 1], acc1);
            acc2 = dot2acc(__builtin_amdgcn_readlane(pk, 2 * k + 4), Ep[k + 2], acc2);
            acc3 = dot2acc(__builtin_amdgcn_readlane(pk, 2 * k + 6), Ep[k + 3], acc3);
        }
        const float S  = (acc0 + acc1) + (acc2 + acc3);
        const float S0 = bcast_lane0(S);
        const float rs = fast_rcp(S0);
        const float lg = __logf(S0);              // wave-uniform, off w-path
        const float wnew = (e * rs) * S;

        const bool upd = (mk != 0);
        w = (upd && valid) ? wnew : w;            // dummy lanes stay 0
        C = upd ? (C + em0 + lg) : C;

        pk = pack_pairs(w);
    }

    // denominator = C + log( sum_j w[j] * exp(end[j]) )
    float v = valid ? (w * __expf(end_tr[jc])) : 0.f;
    #pragma unroll
    for (int off = 32; off > 0; off >>= 1) v += __shfl_xor(v, off);
    if (lane == 0) denom_out[b] = C + __logf(v);
}

// ---------------------------------------------------------------------------
// Kernel 2: numerator partial sums over t-chunks (runtime chunk count).
// gid = c*1024 + b; chunk c covers t in [c*csz, (c+1)*csz).
// ---------------------------------------------------------------------------
__global__ __launch_bounds__(256) void crf_score_partial(
    const float* __restrict__ emissions,
    const int* __restrict__ tags,             // (L,B)
    const int* __restrict__ mask,             // (L,B)
    const float* __restrict__ trans,          // (T,T)
    float* __restrict__ part,                 // (nchunk, B)
    int* __restrict__ cnt,                    // (nchunk, B)
    int csz)
{
    const int gid = blockIdx.x * blockDim.x + threadIdx.x;
    const int b = gid & (BATCH - 1);
    const int c = gid >> 10;
    const int t0 = c * csz;
    const int t1 = t0 + csz;

    float sc = 0.f;
    int ct = 0;
    const int tstart = (t0 == 0) ? 1 : t0;
    if (t0 == 0) ct += mask[b] ? 1 : 0;       // t = 0 contributes to count only

    int tag_prev = tags[(tstart - 1) * BATCH + b];
    for (int t = tstart; t < t1; ++t) {
        const int tag = tags[t * BATCH + b];
        const int mt = mask[t * BATCH + b];
        if (mt) {
            sc += trans[tag_prev * T + tag]
                + emissions[((size_t)t * BATCH + b) * T + tag];
            ct += 1;
        }
        tag_prev = tag;                       // raw previous tag, per reference
    }
    part[gid] = sc;
    cnt[gid] = ct;
}

// ---------------------------------------------------------------------------
// Kernel 3: combine partials + start/end terms, subtract denominator, mean.
// ---------------------------------------------------------------------------
__global__ __launch_bounds__(1024) void crf_combine(
    const float* __restrict__ emissions,
    const int* __restrict__ tags,
    const float* __restrict__ start_tr,
    const float* __restrict__ end_tr,
    const float* __restrict__ part,
    const int* __restrict__ cnt,
    const float* __restrict__ denom,
    float* __restrict__ out,
    int nchunk)
{
    const int b = threadIdx.x;

    const int tag0 = tags[b];
    float sc = start_tr[tag0] + emissions[(size_t)b * T + tag0];
    int ct = 0;
    for (int c = 0; c < nchunk; ++c) {
        sc += part[c * BATCH + b];
        ct += cnt[c * BATCH + b];
    }
    if (ct < 1) ct = 1;                        // guard (mask all-zero)
    const int last_tag = tags[(ct - 1) * BATCH + b];
    sc += end_tr[last_tag];

    const float llh = sc - denom[b];

    __shared__ float red[1024];
    red[b] = llh;
    __syncthreads();
    #pragma unroll
    for (int s = 512; s > 0; s >>= 1) {
        if (b < s) red[b] += red[b + s];
        __syncthreads();
    }
    if (b == 0) out[0] = red[0] / (float)BATCH;
}

extern "C" void kernel_launch(void* const* d_in, const int* in_sizes, int n_in,
                              void* d_out, int out_size, void* d_ws, size_t ws_size,
                              hipStream_t stream) {
    const float* emissions        = (const float*)d_in[0];
    const int* tags               = (const int*)d_in[1];
    const int* mask               = (const int*)d_in[2];
    const float* start_tr         = (const float*)d_in[3];
    const float* end_tr           = (const float*)d_in[4];
    const float* trans            = (const float*)d_in[5];
    float* out                    = (float*)d_out;

    // scale numerator chunk count to available workspace
    const int nchunk = (ws_size >= (size_t)(BATCH * 4 + 32 * BATCH * 8 + 64)) ? 32 : 8;
    const int csz    = LSEQ / nchunk;

    float* denom = (float*)d_ws;               // B floats
    float* part  = denom + BATCH;              // nchunk*B floats
    int*   cnt   = (int*)(part + nchunk * BATCH); // nchunk*B ints

    crf_forward<<<256, 256, 0, stream>>>(emissions, mask, start_tr, end_tr, trans, denom);
    crf_score_partial<<<nchunk * BATCH / 256, 256, 0, stream>>>(
        emissions, tags, mask, trans, part, cnt, csz);
    crf_combine<<<1, 1024, 0, stream>>>(emissions, tags, start_tr, end_tr,
                                        part, cnt, denom, out, nchunk);
}